// Round 7
// baseline (13.695 us; speedup 1.0000x reference)
//
#include <hip/hip_runtime.h>
#include <hip/hip_bf16.h>

#define NGRID  2048
#define BATCH  4
#define CIN    16
#define COUT   32
#define NOUT   1024
#define NT     16                     // targets per block
#define NW     16                     // waves per block = K slices
#define KSL    (NGRID / NW)           // 128 grid points per wave
#define KSTEP  (KSL / 32)             // 4 MFMA K-steps per wave
#define NBLK   (BATCH * (NOUT / NT))  // 256 blocks
#define PADT   18                     // part[] inner pad: kb-stride 72B = 8 banks -> 2-way (free)

typedef short bf16x8 __attribute__((ext_vector_type(8)));
typedef float f32x4  __attribute__((ext_vector_type(4)));

__device__ __forceinline__ float fexp2(float x) {
#if __has_builtin(__builtin_amdgcn_exp2f)
    return __builtin_amdgcn_exp2f(x);
#else
    return exp2f(x);
#endif
}

union ABfrag { bf16x8 v; short2 s2[4]; };

__device__ __forceinline__ short2 pk_bf16(float lo, float hi) {
    __hip_bfloat162 h = __float22bfloat162_rn(float2{lo, hi});
    short2 r;
    __builtin_memcpy(&r, &h, 4);
    return r;
}

// Block = (batch, 16 targets), 16 waves; wave wv owns grid K-slice [wv*128, wv*128+128).
// z = r_bf16 @ w_bf16 via mfma_f32_16x16x32_bf16 (uniform-sigma fast path).
//   A: row c = lane&15, k = (lane>>4)*8 + j ; B: col t = lane&15, same k
//   C/D (m89-verified): col t = lane&15, row c = (lane>>4)*4 + reg
// Scheduling: r-loads issued at top; A-cvt + a2/uni overlap the minmax barrier.
__global__ __launch_bounds__(1024) void conv_decoder_mfma(
        const float* __restrict__ r,      // (B, CIN, NGRID)
        const float* __restrict__ xc,     // (B*NCTX) = 1024 floats
        const float* __restrict__ xt,     // (B*NOUT) = 4096 floats
        const float* __restrict__ sigma,  // (CIN)
        const float* __restrict__ W,      // (CIN, COUT)
        const float* __restrict__ bias,   // (COUT)
        float* __restrict__ out) {        // (B, NOUT, COUT)
    const int tid  = threadIdx.x;
    const int lane = tid & 63;
    const int wv   = tid >> 6;            // 0..15 = K slice
    const int blk  = blockIdx.x;
    const int b    = blk >> 6;            // 64 target-groups per batch
    const int tg0  = (blk & 63) * NT;

    const int t   = lane & 15;            // target col (B/C); channel row for A
    const int kb  = lane >> 4;            // k-group
    const int wk0 = wv * KSL;

    __shared__ float part[NW][CIN][PADT]; // ~18.4 KB
    __shared__ float zbuf[CIN][PADT];
    __shared__ float smn[NW], smx[NW];

    const float* rb   = r + (size_t)b * (CIN * NGRID);
    const float* rrow = rb + t * NGRID + wk0 + kb * 8;

    // ---- 1. issue all A-path loads up front (minmax-independent) ----
    float4 r0[KSTEP], r1[KSTEP];
    #pragma unroll
    for (int kk = 0; kk < KSTEP; ++kk) {
        r0[kk] = *reinterpret_cast<const float4*>(rrow + kk * 32);
        r1[kk] = *reinterpret_cast<const float4*>(rrow + kk * 32 + 4);
    }
    const float xT = xt[b * NOUT + tg0 + t];

    // ---- 2. block-wide min/max over xc (1024) + xt (4096) ----
    float mn, mx;
    {
        float v = xc[tid];
        mn = v; mx = v;
        float4 u = *reinterpret_cast<const float4*>(xt + tid * 4);
        mn = fminf(mn, fminf(fminf(u.x, u.y), fminf(u.z, u.w)));
        mx = fmaxf(mx, fmaxf(fmaxf(u.x, u.y), fmaxf(u.z, u.w)));
        #pragma unroll
        for (int off = 32; off; off >>= 1) {
            mn = fminf(mn, __shfl_xor(mn, off));
            mx = fmaxf(mx, __shfl_xor(mx, off));
        }
    }
    if (lane == 0) { smn[wv] = mn; smx[wv] = mx; }

    // ---- 3. overlap barrier latency: A-frag cvt + sigma coefficients ----
    ABfrag A[KSTEP];
    #pragma unroll
    for (int kk = 0; kk < KSTEP; ++kk) {
        A[kk].s2[0] = pk_bf16(r0[kk].x, r0[kk].y);
        A[kk].s2[1] = pk_bf16(r0[kk].z, r0[kk].w);
        A[kk].s2[2] = pk_bf16(r1[kk].x, r1[kk].y);
        A[kk].s2[3] = pk_bf16(r1[kk].z, r1[kk].w);
    }
    const float LOG2E = 1.4426950408889634f;
    float a2[CIN];
    #pragma unroll
    for (int c = 0; c < CIN; ++c)
        a2[c] = -0.5f * LOG2E * fexp2(-2.0f * LOG2E * sigma[c]);  // exp2(a2*d^2)
    bool uni = true;
    #pragma unroll
    for (int c = 1; c < CIN; ++c) uni = uni && (a2[c] == a2[0]);

    __syncthreads();
    #pragma unroll
    for (int w2 = 0; w2 < NW; ++w2) {
        mn = fminf(mn, smn[w2]);
        mx = fmaxf(mx, smx[w2]);
    }
    const float xmin = mn - 0.1f;
    const float step = ((mx + 0.1f) - xmin) * (1.0f / (float)(NGRID - 1));

    f32x4 acc = {0.0f, 0.0f, 0.0f, 0.0f};

    if (uni) {
        const float s     = sqrtf(-a2[0]);   // w = exp2(-(s*g - s*x)^2)
        const float sxm   = s * xmin;
        const float sstep = s * step;
        const float sx    = s * xT;

        #pragma unroll
        for (int kk = 0; kk < KSTEP; ++kk) {
            const int k0 = wk0 + kk * 32;
            float wgt[8];
            #pragma unroll
            for (int j = 0; j < 8; ++j) {
                float gi = (float)(k0 + kb * 8 + j);
                float d  = __builtin_fmaf(sstep, gi, sxm) - sx;
                wgt[j] = fexp2(-(d * d));
            }
            ABfrag Bf;
            #pragma unroll
            for (int p = 0; p < 4; ++p)
                Bf.s2[p] = pk_bf16(wgt[2 * p], wgt[2 * p + 1]);
            acc = __builtin_amdgcn_mfma_f32_16x16x32_bf16(A[kk].v, Bf.v, acc, 0, 0, 0);
        }
    } else {
        // generic per-channel-sigma fallback (f32 VALU), same C-frag layout
        #pragma unroll 1
        for (int k = 0; k < KSL; ++k) {
            float g  = xmin + step * (float)(wk0 + k);
            float d  = g - xT;
            float d2 = d * d;
            #pragma unroll
            for (int reg = 0; reg < 4; ++reg) {
                int c = kb * 4 + reg;
                acc[reg] += rb[c * NGRID + wk0 + k] * fexp2(a2[c] * d2);
            }
        }
    }

    // ---- write C fragments; cross-wave K reduction ----
    #pragma unroll
    for (int reg = 0; reg < 4; ++reg)
        part[wv][kb * 4 + reg][t] = acc[reg];
    __syncthreads();

    if (tid < CIN * NT) {                 // 256 threads: one (c,t) each
        const int c  = tid >> 4;
        const int tt = tid & 15;
        float z = 0.0f;
        #pragma unroll
        for (int w2 = 0; w2 < NW; ++w2) z += part[w2][c][tt];
        zbuf[c][tt] = z;
    }
    __syncthreads();

    // ---- epilogue: 512 threads, one (t, cout) each ----
    if (tid < NT * COUT) {
        const int tt = tid >> 5;
        const int co = tid & 31;
        float o = bias[co];
        #pragma unroll
        for (int c = 0; c < CIN; ++c)
            o = __builtin_fmaf(zbuf[c][tt], W[c * COUT + co], o);
        out[((size_t)b * NOUT + tg0 + tt) * COUT + co] = o;
    }
}

extern "C" void kernel_launch(void* const* d_in, const int* in_sizes, int n_in,
                              void* d_out, int out_size, void* d_ws, size_t ws_size,
                              hipStream_t stream) {
    const float* r  = (const float*)d_in[0];  // (4,16,2048)
    const float* xc = (const float*)d_in[1];  // (4,256,1)
    // d_in[2] = y_context — unused by the reference
    const float* xt = (const float*)d_in[3];  // (4,1024,1)
    const float* sg = (const float*)d_in[4];  // (16)
    const float* W  = (const float*)d_in[5];  // (16,32)
    const float* bs = (const float*)d_in[6];  // (32)
    float* out = (float*)d_out;               // (4,1024,32) f32

    conv_decoder_mfma<<<NBLK, 1024, 0, stream>>>(r, xc, xt, sg, W, bs, out);
}